// Round 1
// baseline (179.836 us; speedup 1.0000x reference)
//
#include <hip/hip_runtime.h>
#include <stdint.h>

#define BATCH   2048
#define KDIM    4096
#define NDIM    11008

#define BM 128
#define BN 128
#define BK 64

typedef __attribute__((ext_vector_type(4))) int i32x4;

typedef const __attribute__((address_space(1))) char glob_char;
typedef __attribute__((address_space(3))) char lds_char;

__device__ __forceinline__ unsigned pack4(i32x4 v) {
  return  ((unsigned)v.x & 0xFFu)
        | (((unsigned)v.y & 0xFFu) << 8)
        | (((unsigned)v.z & 0xFFu) << 16)
        | (((unsigned)v.w)         << 24);
}

// int32 (values in [-128,127]) -> packed int8, 4 elements per thread
__global__ __launch_bounds__(256) void convert_i32_i8(const int* __restrict__ src,
                                                      unsigned* __restrict__ dst,
                                                      int n4) {
  int idx = blockIdx.x * 256 + threadIdx.x;
  if (idx >= n4) return;
  i32x4 v = ((const i32x4*)src)[idx];
  dst[idx] = pack4(v);
}

// C[M=2048][N=11008] = A[2048][4096] * W[11008][4096]^T, int8 MFMA.
// 128x128 tile, BK=64, 4 waves each computing a 64x64 quadrant as 4x4
// fragments of mfma_i32_16x16x64_i8.
// LDS slot swizzle: within each 64B row (4 slots of 16B), physical slot
// p holds logical slot p ^ ((row>>1)&3). Applied on the global SOURCE
// address for global_load_lds (linear dest) and on the ds_read address.
template<bool FUSED>
__global__ __launch_bounds__(256) void ternary_gemm(const void* __restrict__ Ap,
                                                    const void* __restrict__ Bp,
                                                    const float* __restrict__ scale,
                                                    const float* __restrict__ bias,
                                                    float* __restrict__ out) {
  __shared__ char lds[2 * BM * BK];   // A tile [128][64] i8, then B tile [128][64] i8

  const int tid  = threadIdx.x;
  const int wid  = tid >> 6;
  const int lane = tid & 63;

  // XCD-aware bijective swizzle (gridDim.x = 1376, 1376 % 8 == 0)
  const int nwg = gridDim.x;
  const int cpx = nwg >> 3;
  const int wg  = (blockIdx.x & 7) * cpx + (blockIdx.x >> 3);
  const int ntiles = NDIM / BN;           // 86
  const int mt = wg / ntiles;
  const int nt = wg % ntiles;
  const int arow0 = mt * BM;
  const int brow0 = nt * BN;

  const int wr = wid >> 1;                // 0..1 : 64-row half
  const int wc = wid & 1;                 // 0..1 : 64-col half

  i32x4 acc[4][4];
#pragma unroll
  for (int m = 0; m < 4; ++m)
#pragma unroll
    for (int n = 0; n < 4; ++n)
      acc[m][n] = (i32x4){0, 0, 0, 0};

  const int rsub = lane & 15;             // fragment row-in-16
  const int sgrp = lane >> 4;             // logical k-slot 0..3

  for (int ks = 0; ks < KDIM / BK; ++ks) {
    const int k0 = ks * BK;

    if (FUSED) {
      const int* A32 = (const int*)Ap;
      const int* B32 = (const int*)Bp;
#pragma unroll
      for (int c = 0; c < 2; ++c) {
        const int off = c * 4096 + wid * 1024 + lane * 16;  // linear byte in tile
        const int row = off >> 6;
        const int p   = (off >> 4) & 3;
        const int sl  = p ^ ((row >> 1) & 3);
        {
          const int* g = A32 + (size_t)(arow0 + row) * KDIM + k0 + sl * 16;
          i32x4 w0 = ((const i32x4*)g)[0];
          i32x4 w1 = ((const i32x4*)g)[1];
          i32x4 w2 = ((const i32x4*)g)[2];
          i32x4 w3 = ((const i32x4*)g)[3];
          i32x4 pk = (i32x4){(int)pack4(w0), (int)pack4(w1), (int)pack4(w2), (int)pack4(w3)};
          *(i32x4*)(lds + off) = pk;
        }
        {
          const int* g = B32 + (size_t)(brow0 + row) * KDIM + k0 + sl * 16;
          i32x4 w0 = ((const i32x4*)g)[0];
          i32x4 w1 = ((const i32x4*)g)[1];
          i32x4 w2 = ((const i32x4*)g)[2];
          i32x4 w3 = ((const i32x4*)g)[3];
          i32x4 pk = (i32x4){(int)pack4(w0), (int)pack4(w1), (int)pack4(w2), (int)pack4(w3)};
          *(i32x4*)(lds + 8192 + off) = pk;
        }
      }
    } else {
      const char* A8 = (const char*)Ap;
      const char* B8 = (const char*)Bp;
#pragma unroll
      for (int c = 0; c < 2; ++c) {
        const int off = c * 4096 + wid * 1024 + lane * 16;
        const int row = off >> 6;
        const int p   = (off >> 4) & 3;
        const int sl  = p ^ ((row >> 1) & 3);
        __builtin_amdgcn_global_load_lds(
            (glob_char*)(A8 + (size_t)(arow0 + row) * KDIM + k0 + sl * 16),
            (lds_char*)(lds + c * 4096 + wid * 1024), 16, 0, 0);
        __builtin_amdgcn_global_load_lds(
            (glob_char*)(B8 + (size_t)(brow0 + row) * KDIM + k0 + sl * 16),
            (lds_char*)(lds + 8192 + c * 4096 + wid * 1024), 16, 0, 0);
      }
    }
    __syncthreads();

    i32x4 af[4], bf[4];
#pragma unroll
    for (int m = 0; m < 4; ++m) {
      const int row = wr * 64 + m * 16 + rsub;
      const int p   = sgrp ^ ((row >> 1) & 3);
      af[m] = *(const i32x4*)(lds + row * 64 + p * 16);
    }
#pragma unroll
    for (int n = 0; n < 4; ++n) {
      const int row = wc * 64 + n * 16 + rsub;
      const int p   = sgrp ^ ((row >> 1) & 3);
      bf[n] = *(const i32x4*)(lds + 8192 + row * 64 + p * 16);
    }
#pragma unroll
    for (int m = 0; m < 4; ++m)
#pragma unroll
      for (int n = 0; n < 4; ++n)
        acc[m][n] = __builtin_amdgcn_mfma_i32_16x16x64_i8(af[m], bf[n], acc[m][n], 0, 0, 0);
    __syncthreads();
  }

  // Epilogue: C/D layout col = lane&15, row = (lane>>4)*4 + reg
  const int crow = (lane >> 4) * 4;
#pragma unroll
  for (int n = 0; n < 4; ++n) {
    const int col = brow0 + wc * 64 + n * 16 + (lane & 15);
    const float sc = scale[col];
    const float bs = bias[col];
#pragma unroll
    for (int m = 0; m < 4; ++m) {
      const int r0 = arow0 + wr * 64 + m * 16 + crow;
#pragma unroll
      for (int j = 0; j < 4; ++j) {
        out[(size_t)(r0 + j) * NDIM + col] = (float)acc[m][n][j] * sc + bs;
      }
    }
  }
}

extern "C" void kernel_launch(void* const* d_in, const int* in_sizes, int n_in,
                              void* d_out, int out_size, void* d_ws, size_t ws_size,
                              hipStream_t stream) {
  const int*   input  = (const int*)d_in[0];     // [2048][4096] int32
  const int*   weight = (const int*)d_in[1];     // [11008][4096] int32 in {-1,0,1}
  const float* scale  = (const float*)d_in[2];   // [11008]
  const float* bias   = (const float*)d_in[3];   // [11008]
  float*       out    = (float*)d_out;           // [2048][11008] fp32

  const size_t needA = (size_t)BATCH * KDIM;     // 8 MB int8
  const size_t needB = (size_t)NDIM * KDIM;      // 44 MB int8

  const dim3 grid((BATCH / BM) * (NDIM / BN));   // 16*86 = 1376
  const dim3 block(256);

  if (ws_size >= needA + needB) {
    char* A8 = (char*)d_ws;
    char* B8 = A8 + needA;
    const int nA4 = (int)(needA / 4);
    const int nB4 = (int)(needB / 4);
    convert_i32_i8<<<(nA4 + 255) / 256, 256, 0, stream>>>(input, (unsigned*)A8, nA4);
    convert_i32_i8<<<(nB4 + 255) / 256, 256, 0, stream>>>(weight, (unsigned*)B8, nB4);
    ternary_gemm<false><<<grid, block, 0, stream>>>(A8, B8, scale, bias, out);
  } else {
    ternary_gemm<true><<<grid, block, 0, stream>>>(input, weight, scale, bias, out);
  }
}

// Round 2
// 157.946 us; speedup vs baseline: 1.1386x; 1.1386x over previous
//
#include <hip/hip_runtime.h>
#include <stdint.h>

#define BATCH   2048
#define KDIM    4096
#define NDIM    11008

#define BM 128
#define BN 256
#define BK 64
#define NT (KDIM / BK)            // 64 K-tiles
#define BUF_BYTES 24576           // A: 128*64=8192, B: 256*64=16384
#define A_OFF 0
#define B_OFF 8192

typedef __attribute__((ext_vector_type(4))) int i32x4;

typedef const __attribute__((address_space(1))) char glob_char;
typedef __attribute__((address_space(3))) char lds_char;

__device__ __forceinline__ unsigned pack4(i32x4 v) {
  return  ((unsigned)v.x & 0xFFu)
        | (((unsigned)v.y & 0xFFu) << 8)
        | (((unsigned)v.z & 0xFFu) << 16)
        | (((unsigned)v.w)         << 24);
}

// int32 (values in [-128,127]) -> packed int8, 4 elements per thread
__global__ __launch_bounds__(256) void convert_i32_i8(const int* __restrict__ src,
                                                      unsigned* __restrict__ dst,
                                                      int n4) {
  int idx = blockIdx.x * 256 + threadIdx.x;
  if (idx >= n4) return;
  i32x4 v = ((const i32x4*)src)[idx];
  dst[idx] = pack4(v);
}

// C[2048][11008] = A[2048][4096] * W[11008][4096]^T via mfma_i32_16x16x64_i8.
// 128x256 tile, 8 waves (2x4), per-wave 64x64 (4x4 fragments), BK=64.
// 3 rotating LDS buffers, prefetch depth 2, counted s_waitcnt vmcnt(3),
// raw s_barrier (no vmcnt(0) drain), setprio(1) around the MFMA cluster.
// LDS slot swizzle (validated r0, 0 bank conflicts): within each 64B row
// (4 slots of 16B), physical slot p holds logical slot p ^ ((row>>1)&3);
// applied on the global SOURCE (global_load_lds dest must be linear) and
// on the ds_read address.
__global__ __launch_bounds__(512, 2) void ternary_gemm(const char* __restrict__ A8,
                                                       const char* __restrict__ B8,
                                                       const float* __restrict__ scale,
                                                       const float* __restrict__ bias,
                                                       float* __restrict__ out) {
  __shared__ char lds[3 * BUF_BYTES];

  const int tid  = threadIdx.x;
  const int wid  = tid >> 6;
  const int lane = tid & 63;

  // XCD-aware swizzle; gridDim.x = 688, 688 % 8 == 0 -> bijective
  const int nwg = gridDim.x;
  const int cpx = nwg >> 3;
  const int wg  = (blockIdx.x & 7) * cpx + (blockIdx.x >> 3);
  // consecutive wg share the N-panel (B stays L2/LLC-hot; A re-sweeps hit LLC)
  const int mt = wg & 15;          // 16 M-tiles
  const int nt = wg >> 4;          // 43 N-tiles
  const int arow0 = mt * BM;
  const int brow0 = nt * BN;

  const int wr = wid >> 2;         // 0..1 : 64-row half of the 128 M rows
  const int wc = wid & 3;          // 0..3 : 64-col quarter of the 256 N cols
  const int rsub = lane & 15;
  const int sgrp = lane >> 4;      // k-slot 0..3 (16 i8 each)

  // per-tile staging: 3 global_load_lds per thread (1 A round + 2 B rounds)
  auto stage = [&](int bufi, int kt) {
    char* base = lds + bufi * BUF_BYTES;
    const int k0 = kt * BK;
    {
      const int row = tid >> 2;                       // 0..127
      const int sl  = (tid & 3) ^ ((row >> 1) & 3);
      __builtin_amdgcn_global_load_lds(
          (glob_char*)(A8 + (size_t)(arow0 + row) * KDIM + k0 + sl * 16),
          (lds_char*)(base + A_OFF + wid * 1024), 16, 0, 0);
    }
#pragma unroll
    for (int c = 0; c < 2; ++c) {
      const int row = c * 128 + (tid >> 2);           // 0..255
      const int sl  = (tid & 3) ^ ((row >> 1) & 3);
      __builtin_amdgcn_global_load_lds(
          (glob_char*)(B8 + (size_t)(brow0 + row) * KDIM + k0 + sl * 16),
          (lds_char*)(base + B_OFF + c * 8192 + wid * 1024), 16, 0, 0);
    }
  };

  i32x4 acc[4][4];
#pragma unroll
  for (int m = 0; m < 4; ++m)
#pragma unroll
    for (int n = 0; n < 4; ++n)
      acc[m][n] = (i32x4){0, 0, 0, 0};

  // prologue: stage tiles 0 and 1, wait for tile 0 (3 oldest loads) only
  stage(0, 0);
  stage(1, 1);
  asm volatile("s_waitcnt vmcnt(3)" ::: "memory");
  __builtin_amdgcn_s_barrier();
  __builtin_amdgcn_sched_barrier(0);

  int b0 = 0, b1 = 1, b2 = 2;      // read b0, prefetch into b2

  for (int t = 0; t < NT; ++t) {
    const char* Ab = lds + b0 * BUF_BYTES;

    i32x4 af[4], bf[4];
#pragma unroll
    for (int m = 0; m < 4; ++m) {
      const int row = wr * 64 + m * 16 + rsub;
      const int p   = sgrp ^ ((row >> 1) & 3);
      af[m] = *(const i32x4*)(Ab + A_OFF + row * 64 + p * 16);
    }
#pragma unroll
    for (int n = 0; n < 4; ++n) {
      const int row = wc * 64 + n * 16 + rsub;
      const int p   = sgrp ^ ((row >> 1) & 3);
      bf[n] = *(const i32x4*)(Ab + B_OFF + row * 64 + p * 16);
    }

    // prefetch tile t+2 (clamped dummy at the tail keeps vmcnt counts uniform;
    // dummy lands in a buffer that is never read again)
    int kt2 = t + 2;
    if (kt2 > NT - 1) kt2 = NT - 1;
    stage(b2, kt2);

    __builtin_amdgcn_s_barrier();

    __builtin_amdgcn_s_setprio(1);
#pragma unroll
    for (int m = 0; m < 4; ++m)
#pragma unroll
      for (int n = 0; n < 4; ++n)
        acc[m][n] = __builtin_amdgcn_mfma_i32_16x16x64_i8(af[m], bf[n], acc[m][n], 0, 0, 0);
    __builtin_amdgcn_s_setprio(0);

    // t+1's 3 loads (issued during t-1) must retire; t+2's 3 may stay in flight
    asm volatile("s_waitcnt vmcnt(3)" ::: "memory");
    __builtin_amdgcn_s_barrier();
    __builtin_amdgcn_sched_barrier(0);

    const int tb = b0; b0 = b1; b1 = b2; b2 = tb;
  }

  // Epilogue (validated r0): C/D layout col = lane&15, row = (lane>>4)*4 + reg
  const int crow = sgrp * 4;
#pragma unroll
  for (int n = 0; n < 4; ++n) {
    const int col = brow0 + wc * 64 + n * 16 + rsub;
    const float sc = scale[col];
    const float bs = bias[col];
#pragma unroll
    for (int m = 0; m < 4; ++m) {
      const int r0 = arow0 + wr * 64 + m * 16 + crow;
#pragma unroll
      for (int j = 0; j < 4; ++j) {
        out[(size_t)(r0 + j) * NDIM + col] = (float)acc[m][n][j] * sc + bs;
      }
    }
  }
}

extern "C" void kernel_launch(void* const* d_in, const int* in_sizes, int n_in,
                              void* d_out, int out_size, void* d_ws, size_t ws_size,
                              hipStream_t stream) {
  const int*   input  = (const int*)d_in[0];     // [2048][4096] int32
  const int*   weight = (const int*)d_in[1];     // [11008][4096] int32 in {-1,0,1}
  const float* scale  = (const float*)d_in[2];   // [11008]
  const float* bias   = (const float*)d_in[3];   // [11008]
  float*       out    = (float*)d_out;           // [2048][11008] fp32

  const size_t needA = (size_t)BATCH * KDIM;     // 8 MB int8
  const size_t needB = (size_t)NDIM * KDIM;      // 44 MB int8

  char* A8 = (char*)d_ws;
  char* B8 = A8 + needA;
  const int nA4 = (int)(needA / 4);
  const int nB4 = (int)(needB / 4);
  convert_i32_i8<<<(nA4 + 255) / 256, 256, 0, stream>>>(input, (unsigned*)A8, nA4);
  convert_i32_i8<<<(nB4 + 255) / 256, 256, 0, stream>>>(weight, (unsigned*)B8, nB4);

  const dim3 grid((BATCH / BM) * (NDIM / BN));   // 16 * 43 = 688
  const dim3 block(512);
  ternary_gemm<<<grid, block, 0, stream>>>(A8, B8, scale, bias, out);
  (void)ws_size; (void)n_in; (void)in_sizes; (void)out_size;
}